// Round 10
// baseline (202.002 us; speedup 1.0000x reference)
//
#include <hip/hip_runtime.h>

#define B_    16
#define N_    65536
#define C_    256
#define DIN_  16
#define DOUT_ 16

typedef float f32x4 __attribute__((ext_vector_type(4)));

// workspace layout (floats):
//   s      [B_][DIN_][C_]    = 65536 floats  (s[b][i][k])
//   off    [B_][C_][DOUT_]   = 65536 floats  (b1-prefilled; k_off atomically
//                                             accumulates invN-scaled partials)
//   wd_t   [C_][DIN_*DOUT_]  = 65536 floats  (wd_t[c][i*16+o])
//   c_of_n [N_]              = 65536 ints    (cluster id of source row n)

// ---------------------------------------------------------------------------
// K1: fused prep + cluster sums (gather form — R0-proven, ~34 µs).
//   blocks [0, 4096): gather-style cluster sum for (b, k) — no atomics.
//   blocks [4096, 4352): transpose w_diag[o][i][c] -> wd_t[c][i*16+o]
//   blocks [4352, 4608): c_of_n[P[j]] = j>>8
//   blocks [4608, 4864): off[b][c][o] = b1[o]  (full 65536 coverage)
// ---------------------------------------------------------------------------
__global__ __launch_bounds__(256) void k_sum_prep(
    const float* __restrict__ x, const float* __restrict__ w_diag,
    const int* __restrict__ P, const float* __restrict__ b1,
    float* __restrict__ s, float* __restrict__ wd_t,
    int* __restrict__ c_of_n, float* __restrict__ off)
{
    int bid = blockIdx.x;
    int t = threadIdx.x;
    if (bid >= B_ * C_) {
        int r = bid - B_ * C_;
        if (r < 256) {
            int o = r >> 4, i = r & 15;
            wd_t[t * 256 + i * 16 + o] = w_diag[r * C_ + t];  // coalesced read
        } else if (r < 512) {
            int k = r - 256;
            c_of_n[P[k * 256 + t]] = k;
        } else {
            int m = (r - 512) * 256 + t;   // r-512 in [0,256) -> m in [0,65536)
            off[m] = b1[m & 15];
        }
        return;
    }
    int b = bid >> 8;
    int k = bid & (C_ - 1);
    int q  = t & 3;         // which float4 of the 16-float row
    int rg = t >> 2;        // 0..63 row group
    float4 acc = make_float4(0.f, 0.f, 0.f, 0.f);
    const int jbase = k << 8;
    #pragma unroll
    for (int m = 0; m < 4; ++m) {
        int n = P[jbase + rg + 64 * m];
        const float4* row =
            reinterpret_cast<const float4*>(x + ((size_t)(b * N_ + n)) * DIN_);
        float4 v = row[q];
        acc.x += v.x; acc.y += v.y; acc.z += v.z; acc.w += v.w;
    }
    // butterfly reduce over row-groups within the wave (bits 2..5 of lane id)
    #pragma unroll
    for (int mask = 4; mask <= 32; mask <<= 1) {
        acc.x += __shfl_xor(acc.x, mask, 64);
        acc.y += __shfl_xor(acc.y, mask, 64);
        acc.z += __shfl_xor(acc.z, mask, 64);
        acc.w += __shfl_xor(acc.w, mask, 64);
    }
    __shared__ float4 part[4][4];  // [wave][q]
    int lane = t & 63, wave = t >> 6;
    if (lane < 4) part[wave][lane] = acc;  // lane == q for lanes 0..3
    __syncthreads();
    if (t < 16) {
        int qq = t >> 2, comp = t & 3;
        float v = 0.f;
        #pragma unroll
        for (int w = 0; w < 4; ++w) {
            const float* p = reinterpret_cast<const float*>(&part[w][qq]);
            v += p[comp];
        }
        int i = qq * 4 + comp;
        s[(b * DIN_ + i) * C_ + k] = v;   // s[b][i][k]
    }
}

// ---------------------------------------------------------------------------
// K2 (depth-2 register pipeline): partial over i-half, atomic-accumulated.
//   off[b,c,o] += invN * sum_{i in half, k} w_off[o,i,c,k] * s[b,i,k]
// grid = 2048: c = g&255, o-quad = ((g>>8)&3)*4, i-half = (g>>10)*8.
// 256 threads = 4 waves; wave owns b-quad; lane kq owns k-quad.
// Pipeline: 8 groups of 8 loads (4 w + 4 s); issue group g+1, then
// sched_barrier(0), then FMA group g -> compiler emits counted vmcnt(8)
// (newest group stays in flight across each FMA block). ~95 VGPR ->
// ~5 waves/SIMD: MLP=16/wave AND occupancy, unlike R9's 32-load batch
// (~160 VGPR, 3 waves/SIMD, one vmcnt(0)-style drain per wave).
// Tail: fold-halving wave reduce; lane<16 atomicAdd into b1-prefilled off.
// ---------------------------------------------------------------------------
__global__ __launch_bounds__(256) void k_off(
    const float* __restrict__ w_off, const float* __restrict__ s,
    float* __restrict__ off)
{
    const int g  = (int)blockIdx.x;   // 0..2047
    const int c  = g & 255;
    const int r  = g >> 8;            // 0..7
    const int o0 = (r & 3) * 4;
    const int i0 = (r >> 2) * 8;
    const int t  = threadIdx.x;
    const int kq = t & 63;
    const int b0 = (t >> 6) * 4;      // wave id -> b-quad

    const float4* w4 = reinterpret_cast<const float4*>(w_off);
    const float4* s4 = reinterpret_cast<const float4*>(s);

    // fl4 index of w_off[o][i][c][4kq] = ((o*16+i)*256+c)*64+kq
    //   o-stride 262144, i-stride 16384
    const int wb = ((o0 * 16 + i0) * 256 + c) * 64 + kq;
    // fl4 index of s[b][i][4kq] = (b*16+i)*64+kq ; b-stride 1024, i-stride 64
    const int sb = (b0 * 16 + i0) * 64 + kq;

    float acc[16];   // acc[oo*4 + bb]
    #pragma unroll
    for (int z = 0; z < 16; ++z) acc[z] = 0.f;

    float4 wA0, wA1, wA2, wA3, sA0, sA1, sA2, sA3;
    float4 wB0, wB1, wB2, wB3, sB0, sB1, sB2, sB3;

#define LOADG(W0, W1, W2, W3, S0, S1, S2, S3, II)                              \
    W0 = w4[wb + 0 * 262144 + (II) * 16384];                                   \
    W1 = w4[wb + 1 * 262144 + (II) * 16384];                                   \
    W2 = w4[wb + 2 * 262144 + (II) * 16384];                                   \
    W3 = w4[wb + 3 * 262144 + (II) * 16384];                                   \
    S0 = s4[sb + 0 * 1024 + (II) * 64];                                        \
    S1 = s4[sb + 1 * 1024 + (II) * 64];                                        \
    S2 = s4[sb + 2 * 1024 + (II) * 64];                                        \
    S3 = s4[sb + 3 * 1024 + (II) * 64];

#define FMAG(W0, W1, W2, W3, S0, S1, S2, S3)                                   \
    {                                                                          \
        const float4 ww[4] = {W0, W1, W2, W3};                                 \
        const float4 ss[4] = {S0, S1, S2, S3};                                 \
        _Pragma("unroll")                                                      \
        for (int oo = 0; oo < 4; ++oo)                                         \
            _Pragma("unroll")                                                  \
            for (int bb = 0; bb < 4; ++bb)                                     \
                acc[oo * 4 + bb] += ww[oo].x * ss[bb].x + ww[oo].y * ss[bb].y  \
                                  + ww[oo].z * ss[bb].z + ww[oo].w * ss[bb].w; \
    }

    LOADG(wA0, wA1, wA2, wA3, sA0, sA1, sA2, sA3, 0)
    #pragma unroll
    for (int ii = 0; ii < 8; ii += 2) {
        LOADG(wB0, wB1, wB2, wB3, sB0, sB1, sB2, sB3, ii + 1)
        __builtin_amdgcn_sched_barrier(0);
        FMAG(wA0, wA1, wA2, wA3, sA0, sA1, sA2, sA3)
        if (ii + 2 < 8) {
            LOADG(wA0, wA1, wA2, wA3, sA0, sA1, sA2, sA3, ii + 2)
        }
        __builtin_amdgcn_sched_barrier(0);
        FMAG(wB0, wB1, wB2, wB3, sB0, sB1, sB2, sB3)
    }
#undef LOADG
#undef FMAG

    // fold-halving reduce: 16 values x 64 lanes -> lane<16 holds bitrev4(lane)
#define FOLD(MASK, CNT)                                                        \
    {                                                                          \
        const bool hi_ = (kq & (MASK)) != 0;                                   \
        _Pragma("unroll")                                                      \
        for (int j = 0; j < (CNT); ++j) {                                      \
            float keep = hi_ ? acc[j + (CNT)] : acc[j];                        \
            float send = hi_ ? acc[j] : acc[j + (CNT)];                        \
            acc[j] = keep + __shfl_xor(send, (MASK), 64);                      \
        }                                                                      \
    }
    FOLD(1, 8) FOLD(2, 4) FOLD(4, 2) FOLD(8, 1)
#undef FOLD
    acc[0] += __shfl_xor(acc[0], 16, 64);
    acc[0] += __shfl_xor(acc[0], 32, 64);

    if (kq < 16) {
        int j  = ((kq & 1) << 3) | ((kq & 2) << 1) | ((kq & 4) >> 1) | ((kq & 8) >> 3);
        int oo = j >> 2;
        int bb = j & 3;
        int b  = b0 + bb;
        int o  = o0 + oo;
        atomicAdd(&off[((b << 8) + c) * DOUT_ + o], acc[0] * (1.0f / (float)N_));
    }
}

// ---------------------------------------------------------------------------
// K3: sequential apply. Non-temporal out stores (out never re-read; keep
// x / w_off L3-resident). (unchanged)
// ---------------------------------------------------------------------------
__global__ __launch_bounds__(256) void k_apply_seq(
    const float* __restrict__ x, const int* __restrict__ c_of_n,
    const float* __restrict__ wd_t, const float* __restrict__ off,
    float* __restrict__ out)
{
    int t = threadIdx.x;
    int lr = t >> 2, q = t & 3;
    int n = blockIdx.x * 64 + lr;
    int c = c_of_n[n];

    const float4* wd4 = reinterpret_cast<const float4*>(wd_t);
    float4 wds[16];
    #pragma unroll
    for (int i = 0; i < 16; ++i) wds[i] = wd4[c * 64 + i * 4 + q];

    const float4* x4   = reinterpret_cast<const float4*>(x);
    const float4* off4 = reinterpret_cast<const float4*>(off);
    f32x4* out4        = reinterpret_cast<f32x4*>(out);

    #pragma unroll 2
    for (int b = 0; b < B_; ++b) {
        size_t rowbase = ((size_t)(b * N_ + n)) * 4;
        float4 x0 = x4[rowbase + 0];
        float4 x1 = x4[rowbase + 1];
        float4 x2 = x4[rowbase + 2];
        float4 x3 = x4[rowbase + 3];
        float4 acc = off4[((size_t)((b << 8) + c)) * 4 + q];
        float xv[16];
        xv[0]=x0.x; xv[1]=x0.y; xv[2]=x0.z; xv[3]=x0.w;
        xv[4]=x1.x; xv[5]=x1.y; xv[6]=x1.z; xv[7]=x1.w;
        xv[8]=x2.x; xv[9]=x2.y; xv[10]=x2.z; xv[11]=x2.w;
        xv[12]=x3.x; xv[13]=x3.y; xv[14]=x3.z; xv[15]=x3.w;
        #pragma unroll
        for (int i = 0; i < 16; ++i) {
            acc.x += xv[i] * wds[i].x;
            acc.y += xv[i] * wds[i].y;
            acc.z += xv[i] * wds[i].z;
            acc.w += xv[i] * wds[i].w;
        }
        f32x4 accv;
        accv.x = acc.x; accv.y = acc.y; accv.z = acc.z; accv.w = acc.w;
        __builtin_nontemporal_store(accv, &out4[rowbase + q]);
    }
}

extern "C" void kernel_launch(void* const* d_in, const int* in_sizes, int n_in,
                              void* d_out, int out_size, void* d_ws, size_t ws_size,
                              hipStream_t stream) {
    const float* x      = (const float*)d_in[0];
    const float* w_diag = (const float*)d_in[1];
    const float* w_off  = (const float*)d_in[2];
    const float* b1     = (const float*)d_in[3];
    const int*   P      = (const int*)d_in[4];
    float* out    = (float*)d_out;
    float* s      = (float*)d_ws;          // 65536 floats (s[b][i][k])
    float* off    = s + 65536;             // 65536 floats
    float* wd_t   = off + 65536;           // 65536 floats
    int*   c_of_n = (int*)(wd_t + 65536);  // 65536 ints

    k_sum_prep<<<B_ * C_ + 768, 256, 0, stream>>>(x, w_diag, P, b1,
                                                  s, wd_t, c_of_n, off);
    k_off<<<2048, 256, 0, stream>>>(w_off, s, off);
    k_apply_seq<<<N_ / 64, 256, 0, stream>>>(x, c_of_n, wd_t, off, out);
}